// Round 3
// baseline (1119.527 us; speedup 1.0000x reference)
//
#include <hip/hip_runtime.h>

// Problem constants
#define E_EXPERTS 8
#define CC 4096   // capacity (rows per expert)
#define DD 1024   // d_model
#define FF 4096   // d_ff

typedef __attribute__((ext_vector_type(4))) float f32x4;
typedef __attribute__((ext_vector_type(8))) short s16x8;
typedef __attribute__((ext_vector_type(8))) unsigned short u16x8;

__device__ __forceinline__ unsigned short f2bf(float f) {
  union { float f; unsigned int u; } v; v.f = f;
  unsigned int u = v.u;
  unsigned int r = (u + 0x7fffu + ((u >> 16) & 1u)) >> 16;  // RNE
  return (unsigned short)r;
}

// ---------------- fp32 -> bf16 linear convert (vectorized, grid-stride) ----
__global__ void cvt_kernel(const float* __restrict__ in,
                           unsigned short* __restrict__ out, long n8) {
  long stride = (long)gridDim.x * blockDim.x;
  for (long i = (long)blockIdx.x * blockDim.x + threadIdx.x; i < n8; i += stride) {
    const float* ip = in + i * 8;
    f32x4 a = *(const f32x4*)ip;
    f32x4 b = *(const f32x4*)(ip + 4);
    u16x8 o;
    o[0] = f2bf(a[0]); o[1] = f2bf(a[1]); o[2] = f2bf(a[2]); o[3] = f2bf(a[3]);
    o[4] = f2bf(b[0]); o[5] = f2bf(b[1]); o[6] = f2bf(b[2]); o[7] = f2bf(b[3]);
    *(u16x8*)(out + i * 8) = o;
  }
}

// ---------------- fp32 [R,Cc] -> bf16 [Cc,R] transpose+convert, per expert z
__global__ void transpose_cvt_kernel(const float* __restrict__ in,
                                     unsigned short* __restrict__ out,
                                     int R, int Cc) {
  __shared__ float t[32][33];
  long eoff = (long)blockIdx.z * R * Cc;
  const float* ip = in + eoff;
  unsigned short* op = out + eoff;
  int c0 = blockIdx.x * 32;
  int r0 = blockIdx.y * 32;
  int tx = threadIdx.x;  // 32
  int ty = threadIdx.y;  // 8
#pragma unroll
  for (int i = 0; i < 32; i += 8)
    t[ty + i][tx] = ip[(long)(r0 + ty + i) * Cc + c0 + tx];
  __syncthreads();
#pragma unroll
  for (int i = 0; i < 32; i += 8)
    op[(long)(c0 + ty + i) * R + r0 + tx] = f2bf(t[tx][ty + i]);
}

// ---------------- bf16 GEMM: C[M,N] = A[M,K] * Bt[N,K]^T  (m97 structure) ---
// OUT_MODE 0: fp32 store; OUT_MODE 1: relu + bf16 store
#define GLOAD_LDS(gp, lp)                                          \
  __builtin_amdgcn_global_load_lds(                                \
      (__attribute__((address_space(1))) void*)(gp),               \
      (__attribute__((address_space(3))) void*)(lp), 16, 0, 0)

template <int OUT_MODE>
__global__ __launch_bounds__(256, 2) void gemm_bt_kernel(
    const unsigned short* __restrict__ A,   // [M,K] bf16 row-major (+ e*sA)
    const unsigned short* __restrict__ Bt,  // [N,K] bf16 row-major (+ e*sB)
    void* __restrict__ Cp,                  // [M,N] (+ e*sC)
    int M, int N, int K, long sA, long sB, long sC) {
  __shared__ __align__(16) unsigned short As[128 * 32];
  __shared__ __align__(16) unsigned short Bs[128 * 32];

  const int e = blockIdx.z;
  const unsigned short* Ae = A + (long)e * sA;
  const unsigned short* Be = Bt + (long)e * sB;

  const int tid = threadIdx.x;
  const int wave = tid >> 6;
  const int lane = tid & 63;

  const int brow = blockIdx.y * 128;
  const int bcol = blockIdx.x * 128;

  // staging: each wave's call covers 16 rows x 32 cols (1024 B); lane l ->
  // row srow = l>>2, col (l&3)*8 ; LDS dest = wave-uniform base + lane*16
  const int srow = lane >> 2;
  const int scol = (lane & 3) * 8;
  const long aoff0 = (long)(brow + wave * 16 + srow) * K + scol;
  const long aoff1 = aoff0 + (long)64 * K;
  const long boff0 = (long)(bcol + wave * 16 + srow) * K + scol;
  const long boff1 = boff0 + (long)64 * K;
  unsigned short* asl0 = &As[wave * 16 * 32];
  unsigned short* asl1 = asl0 + 64 * 32;
  unsigned short* bsl0 = &Bs[wave * 16 * 32];
  unsigned short* bsl1 = bsl0 + 64 * 32;

  // wave 2x2 grid over the 128x128 tile; each wave owns 64x64 = 4x4 frags
  const int wr = wave >> 1, wc = wave & 1;
  const int fr = lane & 15;  // fragment row (A) / col (B); also C col
  const int fq = lane >> 4;  // k-quarter; C row group

  f32x4 acc[4][4] = {};

  for (int kt = 0; kt < K; kt += 32) {
    GLOAD_LDS(Ae + aoff0 + kt, asl0);
    GLOAD_LDS(Ae + aoff1 + kt, asl1);
    GLOAD_LDS(Be + boff0 + kt, bsl0);
    GLOAD_LDS(Be + boff1 + kt, bsl1);
    __syncthreads();  // drains vmcnt(0): staged data visible to all waves

    s16x8 af[4], bfr[4];
#pragma unroll
    for (int m = 0; m < 4; ++m)
      af[m] = *(const s16x8*)&As[(wr * 64 + m * 16 + fr) * 32 + fq * 8];
#pragma unroll
    for (int n = 0; n < 4; ++n)
      bfr[n] = *(const s16x8*)&Bs[(wc * 64 + n * 16 + fr) * 32 + fq * 8];

#pragma unroll
    for (int m = 0; m < 4; ++m)
#pragma unroll
      for (int n = 0; n < 4; ++n)
        acc[m][n] = __builtin_amdgcn_mfma_f32_16x16x32_bf16(af[m], bfr[n],
                                                            acc[m][n], 0, 0, 0);
    __syncthreads();  // all waves done reading before next stage overwrites
  }

  // C/D layout (16x16x32 bf16): col = lane&15, row = (lane>>4)*4 + reg
  const int r0 = brow + wr * 64 + fq * 4;
  const int c0 = bcol + wc * 64 + fr;
  if (OUT_MODE == 1) {
    unsigned short* Co = (unsigned short*)Cp + (long)e * sC;
#pragma unroll
    for (int m = 0; m < 4; ++m)
#pragma unroll
      for (int n = 0; n < 4; ++n)
#pragma unroll
        for (int j = 0; j < 4; ++j) {
          float v = acc[m][n][j];
          v = v > 0.f ? v : 0.f;  // fused ReLU
          Co[(long)(r0 + m * 16 + j) * N + (c0 + n * 16)] = f2bf(v);
        }
  } else {
    float* Co = (float*)Cp + (long)e * sC;
#pragma unroll
    for (int m = 0; m < 4; ++m)
#pragma unroll
      for (int n = 0; n < 4; ++n)
#pragma unroll
        for (int j = 0; j < 4; ++j)
          Co[(long)(r0 + m * 16 + j) * N + (c0 + n * 16)] = acc[m][n][j];
  }
}

extern "C" void kernel_launch(void* const* d_in, const int* in_sizes, int n_in,
                              void* d_out, int out_size, void* d_ws,
                              size_t ws_size, hipStream_t stream) {
  (void)in_sizes; (void)n_in; (void)out_size;
  const float* x = (const float*)d_in[0];
  // d_in[1] = experts_capacity_usage: unused by the reference math
  const float* W1 = (const float*)d_in[2];
  const float* W2 = (const float*)d_in[3];
  float* out = (float*)d_out;

  const long CD = (long)CC * DD;  // 4,194,304
  const long DF = (long)DD * FF;  // 4,194,304
  const long CF = (long)CC * FF;  // 16,777,216

  // per-expert chunk bytes: xb + w1t + w2t + h (all bf16)
  const size_t per_e = (size_t)(CD + DF + DF + CF) * 2;  // ~58.7 MB
  int G = 1;
  if (8 * per_e <= ws_size) G = 8;
  else if (4 * per_e <= ws_size) G = 4;
  else if (2 * per_e <= ws_size) G = 2;

  char* p = (char*)d_ws;
  unsigned short* xb = (unsigned short*)p;   p += (size_t)G * CD * 2;
  unsigned short* w1t = (unsigned short*)p;  p += (size_t)G * DF * 2;
  unsigned short* w2t = (unsigned short*)p;  p += (size_t)G * DF * 2;
  unsigned short* h = (unsigned short*)p;

  dim3 tb(32, 8);
  for (int e0 = 0; e0 < E_EXPERTS; e0 += G) {
    // x chunk -> bf16
    cvt_kernel<<<2048, 256, 0, stream>>>(x + (long)e0 * CD, xb,
                                         (long)G * CD / 8);
    // W1 [D,F] -> w1t [F,D] bf16 ; W2 [F,D] -> w2t [D,F] bf16
    transpose_cvt_kernel<<<dim3(FF / 32, DD / 32, G), tb, 0, stream>>>(
        W1 + (long)e0 * DF, w1t, DD, FF);
    transpose_cvt_kernel<<<dim3(DD / 32, FF / 32, G), tb, 0, stream>>>(
        W2 + (long)e0 * DF, w2t, FF, DD);
    // h = relu(x @ W1): M=C, N=F, K=D
    gemm_bt_kernel<1><<<dim3(FF / 128, CC / 128, G), 256, 0, stream>>>(
        xb, w1t, h, CC, FF, DD, CD, DF, CF);
    // y = h @ W2: M=C, N=D, K=F
    gemm_bt_kernel<0><<<dim3(DD / 128, CC / 128, G), 256, 0, stream>>>(
        h, w2t, out + (long)e0 * CD, CC, DD, FF, CF, DF, CD);
  }
}